// Round 5
// baseline (724.516 us; speedup 1.0000x reference)
//
#include <hip/hip_runtime.h>

// Autoregressive FFNN. out[b,0]=0; t=1..511: mi=[x[b,t,:],pred]; h=relu(mi@W1+b1); pred=h@W2+b2.
// B=4096,T=512,F=63. 256 WGs x 512 thr (8 waves), 16 batch rows/WG, persistent, 1 barrier/step.
// - A-frags loaded DIRECTLY from global (L1-cached, 2-step reg prefetch) -> no x staging in LDS.
// - b1 folded into MFMA via A[m][63]=1.0, B[63][n]=b1[n]. pred feedback = VALU fma (pred*W1[63]).
// - Cross-lane reduces via __shfl_xor (R1-proven); only 2 DS b128 ops/wave/step beyond shuffles.

#define TT 512
#define FF 63
#define HID 1024

typedef __attribute__((ext_vector_type(8))) short short8;
typedef __attribute__((ext_vector_type(4))) float f32x4;
typedef __attribute__((ext_vector_type(4))) int i32x4;

struct __attribute__((packed, aligned(4))) uf4 { f32x4 v; };
__device__ __forceinline__ f32x4 ld4u(const float* p) {
  return reinterpret_cast<const uf4*>(p)->v;  // dword-aligned 16B load
}

__device__ __forceinline__ unsigned short f2bf(float f) {
  union { float f; unsigned u; } v; v.f = f;
  unsigned r = v.u + 0x7FFFu + ((v.u >> 16) & 1u);  // RNE
  return (unsigned short)(r >> 16);
}

__device__ __forceinline__ unsigned pk2(float a, float b) {
  return ((unsigned)f2bf(b) << 16) | (unsigned)f2bf(a);
}

// butterfly stage: v[q] += shfl_xor(v[q], M) — masks 1,2,4 stay within each
// 8-lane half-row; mask 8 stays within the 16-lane row. Proven in R1.
template<int M>
__device__ __forceinline__ f32x4 sflxadd4(f32x4 v) {
  f32x4 r;
#pragma unroll
  for (int q = 0; q < 4; ++q) r[q] = v[q] + __shfl_xor(v[q], M, 64);
  return r;
}

__global__ __launch_bounds__(512, 2)
void ffnn_ar_kernel(const float* __restrict__ x,
                    const float* __restrict__ W1,
                    const float* __restrict__ b1,
                    const float* __restrict__ W2,
                    const float* __restrict__ b2p,
                    float* __restrict__ out) {
  __shared__ __align__(16) float lds_part[2][8][20];  // [buf][wave][16 rows + pad4]

  const int tid  = threadIdx.x;
  const int lane = tid & 63;
  const int w    = tid >> 6;
  const int c    = lane & 15;   // batch row within tile / C col-id
  const int g    = lane >> 4;   // k-group 0..3 / C row-block
  const int br   = blockIdx.x * 16;

  // ---- weights (one-time): W1 B-frags bf16 (k=63 slot = b1), W1[63], W2 ----
  short8 bfr[8][2];
  float  w63f[8], w2f[8];
#pragma unroll
  for (int i = 0; i < 8; ++i) {
    const int n = (w * 8 + i) * 16 + c;
#pragma unroll
    for (int ks = 0; ks < 2; ++ks) {
      short8 f;
#pragma unroll
      for (int j = 0; j < 8; ++j) {
        const int k = ks * 32 + g * 8 + j;
        const float val = (k == 63) ? b1[n] : W1[k * HID + n];
        f[j] = (short)f2bf(val);
      }
      bfr[i][ks] = f;
    }
    w63f[i] = W1[63 * HID + n];
    w2f[i]  = W2[n];
  }
  const float b2 = b2p[0];
  const bool  g3 = (g == 3);

  // per-lane x addressing: row = br+c, k-base = g*8
  const float* xp = x + (long)(br + c) * (TT * FF);
  const float* xq = xp + (g3 ? -1 : 0);  // shifted base so a1-high stays in-bounds for g3
  const int k0 = g * 8;
  const long outRow = (long)(br + g * 4 + c) * TT;  // valid when c<4
  const bool wr0 = (w == 0) && (c < 4);

  // prologue: partial buf0 = 0 except wave-0 chunk = -b2 (so pred_0 = 0 after +b2)
  if (tid < 320) reinterpret_cast<float*>(lds_part)[tid] = 0.f;
  if (tid < 16) lds_part[0][0][tid] = -b2;

  // 2-step register prefetch of x
  f32x4 A0, A1, A2, A3, B0, B1, B2, B3;
  { const int o = 1 * FF + k0; A0 = ld4u(xp + o); A1 = ld4u(xp + o + 4); A2 = ld4u(xp + o + 32); A3 = ld4u(xq + o + 36); }
  { const int o = 2 * FF + k0; B0 = ld4u(xp + o); B1 = ld4u(xp + o + 4); B2 = ld4u(xp + o + 32); B3 = ld4u(xq + o + 36); }

  __syncthreads();

#define STEP(T, RD, WRI, L0, L1, L2, L3)                                          \
  {                                                                               \
    /* gather pred_{T-1}: ds_read_b128 + 3 shfl_xor stages (8-wave sum) */        \
    f32x4 pr = *reinterpret_cast<const f32x4*>(&lds_part[RD][c & 7][g * 4]);      \
    pr = sflxadd4<1>(pr); pr = sflxadd4<2>(pr); pr = sflxadd4<4>(pr);             \
    const float p0 = pr[0] + b2, p1 = pr[1] + b2;                                 \
    const float p2 = pr[2] + b2, p3 = pr[3] + b2;                                 \
    /* A-frags from prefetched regs (bf16 pack); k=63 slot = 1.0 for g3 */        \
    const short8 a0 = __builtin_bit_cast(short8, (i32x4){                         \
        (int)pk2(L0[0], L0[1]), (int)pk2(L0[2], L0[3]),                           \
        (int)pk2(L1[0], L1[1]), (int)pk2(L1[2], L1[3])});                         \
    const float e4 = g3 ? L3[1] : L3[0], e5 = g3 ? L3[2] : L3[1];                 \
    const float e6 = g3 ? L3[3] : L3[2], e7 = g3 ? 1.0f : L3[3];                  \
    const short8 a1 = __builtin_bit_cast(short8, (i32x4){                         \
        (int)pk2(L2[0], L2[1]), (int)pk2(L2[2], L2[3]),                           \
        (int)pk2(e4, e5), (int)pk2(e6, e7)});                                     \
    f32x4 acc[8];                                                                 \
    _Pragma("unroll") for (int i = 0; i < 8; ++i) {                               \
      f32x4 z4 = {0.f, 0.f, 0.f, 0.f};                                            \
      z4 = __builtin_amdgcn_mfma_f32_16x16x32_bf16(a0, bfr[i][0], z4, 0, 0, 0);   \
      z4 = __builtin_amdgcn_mfma_f32_16x16x32_bf16(a1, bfr[i][1], z4, 0, 0, 0);   \
      acc[i] = z4;                                                                \
    }                                                                             \
    /* store pred_{T-1} (wave0, lanes c<4 each store row g*4+c) */                \
    if (wr0) out[outRow + ((T) - 1)] =                                            \
        (c & 1) ? ((c & 2) ? p3 : p1) : ((c & 2) ? p2 : p0);                      \
    /* layer2 partial: z = acc(+b1) + pred*w63 ; h=relu ; part += h*w2 */         \
    f32x4 part = {0.f, 0.f, 0.f, 0.f};                                            \
    _Pragma("unroll") for (int i = 0; i < 8; ++i) {                               \
      part[0] = fmaf(fmaxf(fmaf(p0, w63f[i], acc[i][0]), 0.f), w2f[i], part[0]);  \
      part[1] = fmaf(fmaxf(fmaf(p1, w63f[i], acc[i][1]), 0.f), w2f[i], part[1]);  \
      part[2] = fmaf(fmaxf(fmaf(p2, w63f[i], acc[i][2]), 0.f), w2f[i], part[2]);  \
      part[3] = fmaf(fmaxf(fmaf(p3, w63f[i], acc[i][3]), 0.f), w2f[i], part[3]);  \
    }                                                                             \
    /* 16-lane butterfly over cols */                                             \
    part = sflxadd4<1>(part); part = sflxadd4<2>(part);                           \
    part = sflxadd4<4>(part); part = sflxadd4<8>(part);                           \
    if (c == 0) *reinterpret_cast<f32x4*>(&lds_part[WRI][w][g * 4]) = part;       \
    /* prefetch x for T+2 */                                                      \
    {                                                                             \
      const int tp = ((T) + 2 < TT) ? (T) + 2 : TT - 1;                           \
      const int o = tp * FF + k0;                                                 \
      L0 = ld4u(xp + o); L1 = ld4u(xp + o + 4);                                   \
      L2 = ld4u(xp + o + 32); L3 = ld4u(xq + o + 36);                             \
    }                                                                             \
    __syncthreads();                                                              \
  }

#pragma unroll 1
  for (int t = 1; t + 1 < TT; t += 2) {
    STEP(t, 0, 1, A0, A1, A2, A3)
    STEP(t + 1, 1, 0, B0, B1, B2, B3)
  }
  STEP(TT - 1, 0, 1, A0, A1, A2, A3)  // t = 511

  // final: gather pred_511 from buf1 and store out[., 511]
  {
    f32x4 pr = *reinterpret_cast<const f32x4*>(&lds_part[1][c & 7][g * 4]);
    pr = sflxadd4<1>(pr); pr = sflxadd4<2>(pr); pr = sflxadd4<4>(pr);
    const float p0 = pr[0] + b2, p1 = pr[1] + b2;
    const float p2 = pr[2] + b2, p3 = pr[3] + b2;
    if (wr0) out[outRow + (TT - 1)] =
        (c & 1) ? ((c & 2) ? p3 : p1) : ((c & 2) ? p2 : p0);
  }
#undef STEP
}

extern "C" void kernel_launch(void* const* d_in, const int* in_sizes, int n_in,
                              void* d_out, int out_size, void* d_ws, size_t ws_size,
                              hipStream_t stream) {
  const float* x   = (const float*)d_in[0];
  // d_in[1] = labels (unused by the reference forward pass)
  const float* W1  = (const float*)d_in[2];
  const float* b1  = (const float*)d_in[3];
  const float* W2  = (const float*)d_in[4];
  const float* b2  = (const float*)d_in[5];
  float* out = (float*)d_out;

  ffnn_ar_kernel<<<256, 512, 0, stream>>>(x, W1, b1, W2, b2, out);
}

// Round 6
// 515.389 us; speedup vs baseline: 1.4058x; 1.4058x over previous
//
#include <hip/hip_runtime.h>

// Autoregressive FFNN. out[b,0]=0; t=1..511: mi=[x[b,t,:],pred]; h=relu(mi@W1+b1); pred=h@W2+b2.
// B=4096,T=512,F=63. 256 WGs x 512 thr (8 waves), 16 batch rows/WG, persistent.
// KEY (R5): raw s_barrier + lgkmcnt(0)-only drain (NOT __syncthreads) so x-prefetch
// global loads stay in flight across the per-step barrier (no vmcnt(0) drain).
// - x staged in LDS as bf16 (converted once/elem), 2-set reg prefetch, ~2 steps of flight.
// - b1 folded into MFMA (A[.][63]=1.0, B-frag k=63 = b1). pred feedback via VALU (pred*W1[63]).
// - pred gather: 8 independent ds_read_b128 + add tree (no dependent shfl chain).

#define TT 512
#define FF 63
#define HID 1024

typedef __attribute__((ext_vector_type(8))) short short8;
typedef __attribute__((ext_vector_type(4))) float f32x4;

__device__ __forceinline__ unsigned short f2bf(float f) {
  union { float f; unsigned u; } v; v.f = f;
  unsigned r = v.u + 0x7FFFu + ((v.u >> 16) & 1u);  // RNE
  return (unsigned short)(r >> 16);
}

// LDS-visibility barrier WITHOUT the vmcnt(0) drain of __syncthreads.
__device__ __forceinline__ void lds_barrier() {
  asm volatile("s_waitcnt lgkmcnt(0)" ::: "memory");
  __builtin_amdgcn_s_barrier();
  asm volatile("" ::: "memory");
}

// butterfly stage: v[q] += shfl_xor(v[q], M) (proven R1/R4)
template<int M>
__device__ __forceinline__ f32x4 sflxadd4(f32x4 v) {
  f32x4 r;
#pragma unroll
  for (int q = 0; q < 4; ++q) r[q] = v[q] + __shfl_xor(v[q], M, 64);
  return r;
}

__global__ __launch_bounds__(512, 2)
void ffnn_ar_kernel(const float* __restrict__ x,
                    const float* __restrict__ W1,
                    const float* __restrict__ b1,
                    const float* __restrict__ W2,
                    const float* __restrict__ b2p,
                    float* __restrict__ out) {
  __shared__ __align__(16) unsigned short lds_A[2][16][72];  // bf16 x-tiles (col63 = 1.0)
  __shared__ __align__(16) float lds_part[2][8][20];         // [buf][wave][16 rows + pad]

  const int tid  = threadIdx.x;
  const int lane = tid & 63;
  const int w    = tid >> 6;
  const int c    = lane & 15;   // A row (batch row) / hidden sub-col
  const int g    = lane >> 4;   // k-group / acc row-block
  const int br   = blockIdx.x * 16;

  // ---- weights (one-time): W1 B-frags bf16 (k=63 slot = b1), W1[63], W2 ----
  short8 bfr[8][2];
  float  w63f[8], w2f[8];
#pragma unroll
  for (int i = 0; i < 8; ++i) {
    const int n = (w * 8 + i) * 16 + c;
#pragma unroll
    for (int ks = 0; ks < 2; ++ks) {
      short8 f;
#pragma unroll
      for (int j = 0; j < 8; ++j) {
        const int k = ks * 32 + g * 8 + j;
        const float val = (k == 63) ? b1[n] : W1[k * HID + n];
        f[j] = (short)f2bf(val);
      }
      bfr[i][ks] = f;
    }
    w63f[i] = W1[63 * HID + n];
    w2f[i]  = W2[n];
  }
  const float b2 = b2p[0];

  // ---- x staging roles: 16 groups of 32 threads, one row each ----
  const int srow = tid >> 5;   // 0..15
  const int sl   = tid & 31;   // 0..31
  const long rowbase = (long)(br + srow) * (TT * FF);

  // prologue: stage x_1 -> buf1; A col63 = bf16(1.0); part buf0 = 0 with chunk0 = -b2
  lds_A[1][srow][sl] = f2bf(x[rowbase + FF + sl]);
  if (sl < 31) lds_A[1][srow][32 + sl] = f2bf(x[rowbase + FF + 32 + sl]);
  if (tid < 16) { lds_A[0][tid][63] = 0x3F80; lds_A[1][tid][63] = 0x3F80; }
  if (tid < 320) reinterpret_cast<float*>(lds_part)[tid] = 0.f;
  if (tid < 16) lds_part[0][0][tid] = -b2;  // sum of chunks + b2 = 0 => pred_0 = 0

  // 2 prefetch sets: S0 = x_2, S1 = x_3 (2-step flight)
  float s0a = x[rowbase + 2 * FF + sl];
  float s0b = (sl < 31) ? x[rowbase + 2 * FF + 32 + sl] : 0.f;
  float s1a = x[rowbase + 3 * FF + sl];
  float s1b = (sl < 31) ? x[rowbase + 3 * FF + 32 + sl] : 0.f;

  lds_barrier();

#define STEP(T, CUR, SA, SB)                                                       \
  {                                                                                \
    /* A-frags for x_T */                                                          \
    const short8 a0 = *reinterpret_cast<const short8*>(&lds_A[CUR][c][g * 8]);     \
    const short8 a1 = *reinterpret_cast<const short8*>(&lds_A[CUR][c][32 + g * 8]);\
    /* pred_{T-1}: 8 independent b128 reads + tree; lane gets rows g*4..g*4+3 */   \
    f32x4 q0 = *reinterpret_cast<const f32x4*>(&lds_part[(CUR) ^ 1][0][g * 4]);    \
    f32x4 q1 = *reinterpret_cast<const f32x4*>(&lds_part[(CUR) ^ 1][1][g * 4]);    \
    f32x4 q2 = *reinterpret_cast<const f32x4*>(&lds_part[(CUR) ^ 1][2][g * 4]);    \
    f32x4 q3 = *reinterpret_cast<const f32x4*>(&lds_part[(CUR) ^ 1][3][g * 4]);    \
    f32x4 q4 = *reinterpret_cast<const f32x4*>(&lds_part[(CUR) ^ 1][4][g * 4]);    \
    f32x4 q5 = *reinterpret_cast<const f32x4*>(&lds_part[(CUR) ^ 1][5][g * 4]);    \
    f32x4 q6 = *reinterpret_cast<const f32x4*>(&lds_part[(CUR) ^ 1][6][g * 4]);    \
    f32x4 q7 = *reinterpret_cast<const f32x4*>(&lds_part[(CUR) ^ 1][7][g * 4]);    \
    f32x4 pr = ((q0 + q1) + (q2 + q3)) + ((q4 + q5) + (q6 + q7));                  \
    const float p0 = pr[0] + b2, p1 = pr[1] + b2;                                  \
    const float p2 = pr[2] + b2, p3 = pr[3] + b2;                                  \
    f32x4 acc[8];                                                                  \
    _Pragma("unroll") for (int i = 0; i < 8; ++i) {                                \
      f32x4 z4 = {0.f, 0.f, 0.f, 0.f};                                             \
      z4 = __builtin_amdgcn_mfma_f32_16x16x32_bf16(a0, bfr[i][0], z4, 0, 0, 0);    \
      z4 = __builtin_amdgcn_mfma_f32_16x16x32_bf16(a1, bfr[i][1], z4, 0, 0, 0);    \
      acc[i] = z4;                                                                 \
    }                                                                              \
    /* store pred_{T-1}: wave0, c==0 lanes own rows g*4+q */                       \
    if (w == 0 && c == 0) {                                                        \
      out[(long)(br + g * 4 + 0) * TT + ((T) - 1)] = p0;                           \
      out[(long)(br + g * 4 + 1) * TT + ((T) - 1)] = p1;                           \
      out[(long)(br + g * 4 + 2) * TT + ((T) - 1)] = p2;                           \
      out[(long)(br + g * 4 + 3) * TT + ((T) - 1)] = p3;                           \
    }                                                                              \
    /* stage x_{T+1} from prefetch set (loaded 2 steps ago) */                     \
    lds_A[(CUR) ^ 1][srow][sl] = f2bf(SA);                                         \
    if (sl < 31) lds_A[(CUR) ^ 1][srow][32 + sl] = f2bf(SB);                       \
    /* reload set <- x_{T+3} (stays in flight across raw barriers) */              \
    {                                                                              \
      const int tp = ((T) + 3 < TT) ? (T) + 3 : TT - 1;                            \
      SA = x[rowbase + (long)tp * FF + sl];                                        \
      if (sl < 31) SB = x[rowbase + (long)tp * FF + 32 + sl];                      \
    }                                                                              \
    /* layer2: z = acc(+b1 in MFMA) + pred*w63 ; h=relu ; part += h*w2 */          \
    f32x4 part = {0.f, 0.f, 0.f, 0.f};                                             \
    _Pragma("unroll") for (int i = 0; i < 8; ++i) {                                \
      part[0] = fmaf(fmaxf(fmaf(p0, w63f[i], acc[i][0]), 0.f), w2f[i], part[0]);   \
      part[1] = fmaf(fmaxf(fmaf(p1, w63f[i], acc[i][1]), 0.f), w2f[i], part[1]);   \
      part[2] = fmaf(fmaxf(fmaf(p2, w63f[i], acc[i][2]), 0.f), w2f[i], part[2]);   \
      part[3] = fmaf(fmaxf(fmaf(p3, w63f[i], acc[i][3]), 0.f), w2f[i], part[3]);   \
    }                                                                              \
    part = sflxadd4<1>(part); part = sflxadd4<2>(part);                            \
    part = sflxadd4<4>(part); part = sflxadd4<8>(part);                            \
    if (c == 0) *reinterpret_cast<f32x4*>(&lds_part[CUR][w][g * 4]) = part;        \
    lds_barrier();                                                                 \
  }

#pragma unroll 1
  for (int t = 1; t + 1 < TT; t += 2) {
    STEP(t, 1, s0a, s0b)
    STEP(t + 1, 0, s1a, s1b)
  }
  STEP(TT - 1, 1, s0a, s0b)  // t = 511 (odd, CUR=1, writes part[1])

  // final: gather pred_511 from part[1] and store out[., 511]
  {
    f32x4 q0 = *reinterpret_cast<const f32x4*>(&lds_part[1][0][g * 4]);
    f32x4 q1 = *reinterpret_cast<const f32x4*>(&lds_part[1][1][g * 4]);
    f32x4 q2 = *reinterpret_cast<const f32x4*>(&lds_part[1][2][g * 4]);
    f32x4 q3 = *reinterpret_cast<const f32x4*>(&lds_part[1][3][g * 4]);
    f32x4 q4 = *reinterpret_cast<const f32x4*>(&lds_part[1][4][g * 4]);
    f32x4 q5 = *reinterpret_cast<const f32x4*>(&lds_part[1][5][g * 4]);
    f32x4 q6 = *reinterpret_cast<const f32x4*>(&lds_part[1][6][g * 4]);
    f32x4 q7 = *reinterpret_cast<const f32x4*>(&lds_part[1][7][g * 4]);
    f32x4 pr = ((q0 + q1) + (q2 + q3)) + ((q4 + q5) + (q6 + q7));
    if (w == 0 && c == 0) {
#pragma unroll
      for (int q = 0; q < 4; ++q)
        out[(long)(br + g * 4 + q) * TT + (TT - 1)] = pr[q] + b2;
    }
  }
#undef STEP
}

extern "C" void kernel_launch(void* const* d_in, const int* in_sizes, int n_in,
                              void* d_out, int out_size, void* d_ws, size_t ws_size,
                              hipStream_t stream) {
  const float* x   = (const float*)d_in[0];
  // d_in[1] = labels (unused by the reference forward pass)
  const float* W1  = (const float*)d_in[2];
  const float* b1  = (const float*)d_in[3];
  const float* W2  = (const float*)d_in[4];
  const float* b2  = (const float*)d_in[5];
  float* out = (float*)d_out;

  ffnn_ar_kernel<<<256, 512, 0, stream>>>(x, W1, b1, W2, b2, out);
}